// Round 1
// 668.689 us; speedup vs baseline: 1.0577x; 1.0577x over previous
//
#include <hip/hip_runtime.h>

// Problem constants (QuantLinear: x[M,K] fp32, qweight[K,N/8] i32, qzeros[G,N/8] i32,
// scales[G,N] fp32, bias[N] fp32, groupsize=128) -> out[M,N] fp32
#define M_DIM 4096
#define N_DIM 12288
#define K_DIM 4096
#define NP    1536        // N/8 packed words per row
#define GS    128

typedef unsigned short ushort_t;
typedef _Float16 half8 __attribute__((ext_vector_type(8)));
typedef unsigned short us8 __attribute__((ext_vector_type(8)));
typedef float f32x16 __attribute__((ext_vector_type(16)));
typedef float f32x4 __attribute__((ext_vector_type(4)));

__device__ __forceinline__ unsigned short f2h(float f) {
  _Float16 h = (_Float16)f;
  return __builtin_bit_cast(unsigned short, h);
}

// async global->LDS, 16B per lane; LDS dst is wave-uniform base + lane*16
#define GLDS16(G, L) __builtin_amdgcn_global_load_lds(                      \
    (const __attribute__((address_space(1))) void*)(G),                     \
    (__attribute__((address_space(3))) void*)(L), 16, 0, 0)

#define DQ_BLOCKS (96 * 64)           // dequant: 96 n-tiles x 64 k-tiles
#define CVT_BLOCKS (M_DIM * K_DIM / 8 / 256)  // 8192

// ---------------------------------------------------------------------------
// Fused prep: blocks [0, DQ_BLOCKS) dequant qweight -> Wt[N,K] f16 (LDS tile
// transpose, R2 design: coalesced reads, 64B-run writes). Blocks after that
// convert x fp32 -> f16. One launch instead of two; tails overlap.
__global__ __launch_bounds__(256) void prep_kernel(
    const int* __restrict__ qw, const int* __restrict__ qz,
    const float* __restrict__ sc, ushort_t* __restrict__ wt,
    const float* __restrict__ x, ushort_t* __restrict__ xb) {
  __shared__ int ldsQ[64 * 16];
  __shared__ int ldsZ[16];
  const int tid = threadIdx.x;
  if (blockIdx.x >= DQ_BLOCKS) {
    // ---- x fp32 -> f16, 8 elements/thread
    int cid = (blockIdx.x - DQ_BLOCKS) * 256 + tid;
    const float4* p = (const float4*)(x + (size_t)cid * 8);
    float4 a = p[0], b = p[1];
    us8 o;
    o[0] = f2h(a.x); o[1] = f2h(a.y); o[2] = f2h(a.z); o[3] = f2h(a.w);
    o[4] = f2h(b.x); o[5] = f2h(b.y); o[6] = f2h(b.z); o[7] = f2h(b.w);
    *(us8*)(xb + (size_t)cid * 8) = o;
    return;
  }
  const int bx = blockIdx.x % 96;     // n-tile
  const int by = blockIdx.x / 96;     // k-tile
  const int k0 = by * 64;
  const int n0 = bx * 128;
  const int w0 = n0 >> 3;       // first packed word column of tile
  const int g  = k0 >> 7;       // 64-k tile lies inside one group (GS=128)
#pragma unroll
  for (int i = 0; i < 4; ++i) {
    int idx = i * 256 + tid;
    int row = idx >> 4, w = idx & 15;      // 16 words = 64B contiguous per row
    ldsQ[row * 16 + (w ^ (row & 15))] = qw[(size_t)(k0 + row) * NP + w0 + w];
  }
  if (tid < 16) ldsZ[tid] = qz[g * NP + w0 + tid];
  __syncthreads();
  const int nl  = tid >> 1;     // local n 0..127
  const int kh  = tid & 1;      // which 32-k half
  const int col = nl >> 3;
  const int j4  = (nl & 7) * 4;
  const int z   = (ldsZ[col] >> j4) & 0xF;
  const float s = sc[(size_t)g * N_DIM + n0 + nl];
  ushort_t* dst = wt + (size_t)(n0 + nl) * K_DIM + k0 + kh * 32;
#pragma unroll
  for (int c = 0; c < 4; ++c) {
    us8 o;
#pragma unroll
    for (int ii = 0; ii < 8; ++ii) {
      int row = kh * 32 + c * 8 + ii;
      int q = (ldsQ[row * 16 + (col ^ (row & 15))] >> j4) & 0xF;
      o[ii] = f2h((float)(q - z) * s);
    }
    *(us8*)(dst + c * 8) = o;
  }
}

// ---------------------------------------------------------------------------
// R4 GEMM: 256x256 tile, BK=64, 512 threads = 8 waves (2m x 4n), wave tile
// 128x64 of mfma_f32_16x16x32_f16. Deep pipeline (T3+T4+T5 per learn_hip
// m201): raw s_barrier + counted vmcnt (never 0 in main loop), setprio(1)
// around the MFMA cluster, per-row XOR bank swizzle applied on the
// global_load_lds SOURCE and on the ds_read side (both-sides, rule 21).
//
// LDS = 2 buffers x {A,B} x 4 k-slices x [256 rows][16 f16] = 128 KiB.
// Staging unit u (= phase index) = one K-step (32 k) of A+B for tile u>>1:
// 32 KiB = 4 global_load_lds_dwordx4 per thread. Unit u lives in buffer
// (u>>1)&1, k-half u&1; unit p+3 (issued at phase p) overwrites unit p-1,
// whose ds_reads drained before the phase p-1 end barrier -> write-safe.
// vmcnt(8) leaves units p+2,p+3 in flight while guaranteeing unit p+1
// landed for the next phase.

// halfword offsets inside lds[]: [buf]*32768 + [op]*16384 + [slice]*4096
//                                + [row]*16 + [slot]*8
__device__ __forceinline__ void stage_unit(
    int u, const ushort_t* __restrict__ Ag, const ushort_t* __restrict__ Bg,
    int m0, int n0, int tid, ushort_t* lds) {
  const int t   = u >> 1;
  const int ks  = u & 1;
  const int b   = t & 1;
  const int kbu = t * 64 + ks * 32;            // k base of this unit
  const int r   = tid >> 1;                    // row 0..255 (2 threads/row)
  // dest is LINEAR (tid*16B); source k-half is inverse-swizzled so that the
  // data landing in slot (tid&1) is global half (tid&1)^((row>>2)&1).
  const int hp  = (tid & 1) ^ ((tid >> 3) & 1);
  const size_t ka = (size_t)kbu + hp * 8;
  ushort_t* dA = lds + b * 32768 + (2 * ks) * 4096 + tid * 8;
  ushort_t* dB = dA + 16384;
  const ushort_t* sA = Ag + (size_t)(m0 + r) * K_DIM + ka;
  const ushort_t* sB = Bg + (size_t)(n0 + r) * K_DIM + ka;
  GLDS16(sA,      dA);          // A slice 2ks
  GLDS16(sA + 16, dA + 4096);   // A slice 2ks+1
  GLDS16(sB,      dB);          // B slice 2ks
  GLDS16(sB + 16, dB + 4096);   // B slice 2ks+1
}

template <int VN, bool STG>
__device__ __forceinline__ void gemm_phase(
    int p, const ushort_t* __restrict__ Ag, const ushort_t* __restrict__ Bg,
    int m0, int n0, int tid, ushort_t* lds, f32x4 (&acc)[8][4]) {
  const int lane = tid & 63;
  const int wid  = tid >> 6;
  const int wm   = wid & 1;        // wave row (m) 0..1
  const int wn   = wid >> 1;       // wave col (n) 0..3
  const int ks   = p & 1;
  const int b    = (p >> 1) & 1;
  // A frag: row = lane&15, k = (lane>>4)*8 + j  (16x16x32 f16 layout).
  // chunk c = lane>>4 -> slice 2ks+(c>>1), k-half h=c&1, slot = h^((row>>2)&1).
  const int c  = lane >> 4;
  const int rl = lane & 15;
  const int sg = (c & 1) ^ ((rl >> 2) & 1);
  const ushort_t* base = lds + b * 32768 + (2 * ks + (c >> 1)) * 4096 + sg * 8;
  const ushort_t* pa = base + (wm * 128 + rl) * 16;
  const ushort_t* pb = base + 16384 + (wn * 64 + rl) * 16;
  half8 af[8], bf[4];
#pragma unroll
  for (int i = 0; i < 8; ++i) af[i] = *(const half8*)(pa + i * 256);
#pragma unroll
  for (int j = 0; j < 4; ++j) bf[j] = *(const half8*)(pb + j * 256);
  if constexpr (STG) stage_unit(p + 3, Ag, Bg, m0, n0, tid, lds);
  __builtin_amdgcn_s_barrier();
  asm volatile("s_waitcnt lgkmcnt(0)" ::: "memory");
  __builtin_amdgcn_sched_barrier(0);   // rule 18: keep MFMA below the wait
  __builtin_amdgcn_s_setprio(1);
#pragma unroll
  for (int i = 0; i < 8; ++i)
#pragma unroll
    for (int j = 0; j < 4; ++j)
      acc[i][j] = __builtin_amdgcn_mfma_f32_16x16x32_f16(af[i], bf[j],
                                                         acc[i][j], 0, 0, 0);
  __builtin_amdgcn_s_setprio(0);
  if constexpr (VN == 8)      asm volatile("s_waitcnt vmcnt(8)" ::: "memory");
  else if constexpr (VN == 4) asm volatile("s_waitcnt vmcnt(4)" ::: "memory");
  else if constexpr (VN == 0) asm volatile("s_waitcnt vmcnt(0)" ::: "memory");
  if constexpr (VN >= 0) {
    __builtin_amdgcn_s_barrier();
    asm volatile("" ::: "memory");     // fence: next phase's ds_reads stay below
  }
}

__global__ __launch_bounds__(512, 2) void gemm256_kernel(
    const ushort_t* __restrict__ Xb, const ushort_t* __restrict__ Wt,
    const float* __restrict__ bias, float* __restrict__ out) {
  __shared__ __align__(16) ushort_t lds[65536];   // 128 KiB
  const int tid = threadIdx.x;
  const int m0  = blockIdx.x * 256;   // m fastest: B panel shared by x-row
  const int n0  = blockIdx.y * 256;
  f32x4 acc[8][4] = {};

  // prologue: units 0,1,2 in flight; wait unit 0 landed (2 units remain)
  stage_unit(0, Xb, Wt, m0, n0, tid, lds);
  stage_unit(1, Xb, Wt, m0, n0, tid, lds);
  stage_unit(2, Xb, Wt, m0, n0, tid, lds);
  asm volatile("s_waitcnt vmcnt(8)" ::: "memory");
  __builtin_amdgcn_s_barrier();
  asm volatile("" ::: "memory");

  // 128 phases = 64 K-tiles x 2 K-steps. Unroll 4 => buf/ks indices fold.
#pragma unroll 4
  for (int p = 0; p < 124; ++p)
    gemm_phase<8, true>(p, Xb, Wt, m0, n0, tid, lds, acc);
  gemm_phase<8, true >(124, Xb, Wt, m0, n0, tid, lds, acc);  // stages unit 127
  gemm_phase<4, false>(125, Xb, Wt, m0, n0, tid, lds, acc);
  gemm_phase<0, false>(126, Xb, Wt, m0, n0, tid, lds, acc);
  gemm_phase<-1, false>(127, Xb, Wt, m0, n0, tid, lds, acc);

  // epilogue: 16x16 C/D layout col=lane&15, row=(lane>>4)*4+reg [m89].
  const int lane = tid & 63;
  const int wm   = (tid >> 6) & 1;
  const int wn   = tid >> 7;
#pragma unroll
  for (int jj = 0; jj < 4; ++jj) {
    int n = n0 + wn * 64 + jj * 16 + (lane & 15);
    float bv = bias[n];
#pragma unroll
    for (int i = 0; i < 8; ++i) {
      int mb = (int)(m0 + wm * 128 + i * 16 + ((lane >> 4) << 2));
#pragma unroll
      for (int r = 0; r < 4; ++r)
        __builtin_nontemporal_store(acc[i][jj][r] + bv,
                                    out + (size_t)(mb + r) * N_DIM + n);
    }
  }
}

// ---------------------------------------------------------------------------
// Fallback GEMM (R3): 128x128x64 block tile, 32x32x16 MFMA — used only when
// the workspace is too small for the materialized-Wt/Xb fast path.
template <int APRE, int BPRE>
__global__ __launch_bounds__(256) void gemm_kernel(
    const ushort_t* __restrict__ Xb, const float* __restrict__ Xf,
    const ushort_t* __restrict__ Wt,
    const int* __restrict__ qw, const int* __restrict__ qz,
    const float* __restrict__ sc,
    const float* __restrict__ bias, float* __restrict__ out) {
  __shared__ __align__(16) ushort_t lsA[128 * 64];
  __shared__ __align__(16) ushort_t lsB[128 * 64];
  const int tid  = threadIdx.x;
  const int lane = tid & 63;
  const int wid  = tid >> 6;
  const int wm   = wid & 1;        // wave row (m) 0..1
  const int wn   = wid >> 1;       // wave col (n) 0..1
  const int m0   = blockIdx.x * 128;   // m varies fastest across blocks
  const int n0   = blockIdx.y * 128;

  f32x16 acc[2][2] = {};

  for (int kt = 0; kt < K_DIM / 64; ++kt) {
    const int kb = kt * 64;
    if constexpr (APRE) {
#pragma unroll
      for (int i = 0; i < 4; ++i) {
        int cid = i * 256 + tid;
        int r = cid >> 3, scol = cid & 7;
        int c = scol ^ (r & 7);
        GLDS16(Xb + (size_t)(m0 + r) * K_DIM + kb + c * 8, lsA + cid * 8);
      }
    } else {
#pragma unroll
      for (int i = 0; i < 4; ++i) {
        int cid = i * 256 + tid;
        int r = cid >> 3, scol = cid & 7;
        int c = scol ^ (r & 7);
        const float* src = Xf + (size_t)(m0 + r) * K_DIM + kb + c * 8;
        float4 a = *(const float4*)src;
        float4 b = *(const float4*)(src + 4);
        us8 o;
        o[0] = f2h(a.x); o[1] = f2h(a.y); o[2] = f2h(a.z); o[3] = f2h(a.w);
        o[4] = f2h(b.x); o[5] = f2h(b.y); o[6] = f2h(b.z); o[7] = f2h(b.w);
        *(us8*)(lsA + cid * 8) = o;
      }
    }
    if constexpr (BPRE) {
#pragma unroll
      for (int i = 0; i < 4; ++i) {
        int cid = i * 256 + tid;
        int r = cid >> 3, scol = cid & 7;
        int c = scol ^ (r & 7);
        GLDS16(Wt + (size_t)(n0 + r) * K_DIM + kb + c * 8, lsB + cid * 8);
      }
    } else {
#pragma unroll
      for (int i = 0; i < 4; ++i) {
        int wi = i * 256 + tid;          // 64 k-rows x 16 words
        int kl = wi >> 4, cw = wi & 15;
        int k = kb + kl;
        int g = k >> 7;
        int qword = qw[(size_t)k * NP + (n0 >> 3) + cw];
        int zword = qz[g * NP + (n0 >> 3) + cw];
        float4 s0 = *(const float4*)(sc + (size_t)g * N_DIM + n0 + cw * 8);
        float4 s1 = *(const float4*)(sc + (size_t)g * N_DIM + n0 + cw * 8 + 4);
        float sv[8] = {s0.x, s0.y, s0.z, s0.w, s1.x, s1.y, s1.z, s1.w};
#pragma unroll
        for (int j = 0; j < 8; ++j) {
          int nl = cw * 8 + j;
          int q = (qword >> (4 * j)) & 0xF;
          int z = (zword >> (4 * j)) & 0xF;
          lsB[nl * 64 + (((kl >> 3) ^ (nl & 7)) << 3) + (kl & 7)] =
              f2h((float)(q - z) * sv[j]);
        }
      }
    }
    __syncthreads();
#pragma unroll
    for (int ks = 0; ks < 4; ++ks) {
      half8 af[2], bfr[2];
      const int h = lane >> 5;
      const int c = ks * 2 + h;
#pragma unroll
      for (int i = 0; i < 2; ++i) {
        int row = wm * 64 + i * 32 + (lane & 31);
        af[i] = *(const half8*)(lsA + (row * 8 + (c ^ (row & 7))) * 8);
      }
#pragma unroll
      for (int jj = 0; jj < 2; ++jj) {
        int row = wn * 64 + jj * 32 + (lane & 31);
        bfr[jj] = *(const half8*)(lsB + (row * 8 + (c ^ (row & 7))) * 8);
      }
#pragma unroll
      for (int i = 0; i < 2; ++i)
#pragma unroll
        for (int jj = 0; jj < 2; ++jj)
          acc[i][jj] = __builtin_amdgcn_mfma_f32_32x32x16_f16(
              af[i], bfr[jj], acc[i][jj], 0, 0, 0);
    }
    __syncthreads();
  }

#pragma unroll
  for (int jj = 0; jj < 2; ++jj) {
    int n = n0 + wn * 64 + jj * 32 + (lane & 31);
    float bv = bias[n];
#pragma unroll
    for (int i = 0; i < 2; ++i) {
      int mbase = m0 + wm * 64 + i * 32 + ((lane >> 5) << 2);
#pragma unroll
      for (int reg = 0; reg < 16; ++reg) {
        int m = mbase + (reg & 3) + ((reg >> 2) << 3);
        __builtin_nontemporal_store(acc[i][jj][reg] + bv,
                                    out + (size_t)m * N_DIM + n);
      }
    }
  }
}

// ---------------------------------------------------------------------------
extern "C" void kernel_launch(void* const* d_in, const int* in_sizes, int n_in,
                              void* d_out, int out_size, void* d_ws, size_t ws_size,
                              hipStream_t stream) {
  const float* x    = (const float*)d_in[0];
  const int*   qw   = (const int*)d_in[1];
  const int*   qz   = (const int*)d_in[2];
  const float* sc   = (const float*)d_in[3];
  const float* bias = (const float*)d_in[4];
  float*       out  = (float*)d_out;
  // d_in[5] = groupsize (=128, hardcoded)

  const size_t WT_BYTES = (size_t)N_DIM * K_DIM * 2;  // 96 MiB
  const size_t XB_BYTES = (size_t)M_DIM * K_DIM * 2;  // 32 MiB
  ushort_t* Wt = (ushort_t*)d_ws;
  ushort_t* Xb = (ushort_t*)((char*)d_ws + WT_BYTES);
  const bool hasWt = ws_size >= WT_BYTES;
  const bool hasXb = ws_size >= WT_BYTES + XB_BYTES;

  if (hasXb) {
    prep_kernel<<<DQ_BLOCKS + CVT_BLOCKS, 256, 0, stream>>>(qw, qz, sc, Wt, x, Xb);
    dim3 grid256(M_DIM / 256, N_DIM / 256);  // (16, 48): m fastest
    gemm256_kernel<<<grid256, 512, 0, stream>>>(Xb, Wt, bias, out);
  } else if (hasWt) {
    dim3 grid(M_DIM / 128, N_DIM / 128);
    prep_kernel<<<DQ_BLOCKS, 256, 0, stream>>>(qw, qz, sc, Wt, x, nullptr);
    gemm_kernel<0, 1><<<grid, 256, 0, stream>>>(nullptr, x, Wt, qw, qz, sc, bias, out);
  } else {
    dim3 grid(M_DIM / 128, N_DIM / 128);
    gemm_kernel<0, 0><<<grid, 256, 0, stream>>>(nullptr, x, nullptr, qw, qz, sc, bias, out);
  }
}

// Round 2
// 638.887 us; speedup vs baseline: 1.1070x; 1.0466x over previous
//
#include <hip/hip_runtime.h>

// Problem constants (QuantLinear: x[M,K] fp32, qweight[K,N/8] i32, qzeros[G,N/8] i32,
// scales[G,N] fp32, bias[N] fp32, groupsize=128) -> out[M,N] fp32
#define M_DIM 4096
#define N_DIM 12288
#define K_DIM 4096
#define NP    1536        // N/8 packed words per row
#define GS    128

typedef unsigned short ushort_t;
typedef _Float16 half8 __attribute__((ext_vector_type(8)));
typedef unsigned short us8 __attribute__((ext_vector_type(8)));
typedef float f32x16 __attribute__((ext_vector_type(16)));
typedef float f32x4 __attribute__((ext_vector_type(4)));

__device__ __forceinline__ unsigned short f2h(float f) {
  _Float16 h = (_Float16)f;
  return __builtin_bit_cast(unsigned short, h);
}

// async global->LDS, 16B per lane; LDS dst is wave-uniform base + lane*16
#define GLDS16(G, L) __builtin_amdgcn_global_load_lds(                      \
    (const __attribute__((address_space(1))) void*)(G),                     \
    (__attribute__((address_space(3))) void*)(L), 16, 0, 0)

#define DQ_BLOCKS (96 * 64)                    // dequant: 96 n-tiles x 64 k-tiles
#define CVT_BLOCKS (M_DIM * K_DIM / 16 / 256)  // 4096 (16 f16 per thread)

// ---------------------------------------------------------------------------
// Fused prep: blocks [0, DQ_BLOCKS) dequant qweight -> Wt[N,K] f16 (LDS tile
// transpose: coalesced reads, 64B-run writes). Blocks after that convert
// x fp32 -> f16. R5: int4 qweight loads (1 instr vs 4), 16-elem cvt threads.
__global__ __launch_bounds__(256) void prep_kernel(
    const int* __restrict__ qw, const int* __restrict__ qz,
    const float* __restrict__ sc, ushort_t* __restrict__ wt,
    const float* __restrict__ x, ushort_t* __restrict__ xb) {
  __shared__ int ldsQ[64 * 16];
  __shared__ int ldsZ[16];
  const int tid = threadIdx.x;
  if (blockIdx.x >= DQ_BLOCKS) {
    // ---- x fp32 -> f16, 16 elements/thread
    size_t cid = (size_t)(blockIdx.x - DQ_BLOCKS) * 256 + tid;
    const float4* p = (const float4*)(x + cid * 16);
    float4 a = p[0], b = p[1], c = p[2], d = p[3];
    us8 o0, o1;
    o0[0] = f2h(a.x); o0[1] = f2h(a.y); o0[2] = f2h(a.z); o0[3] = f2h(a.w);
    o0[4] = f2h(b.x); o0[5] = f2h(b.y); o0[6] = f2h(b.z); o0[7] = f2h(b.w);
    o1[0] = f2h(c.x); o1[1] = f2h(c.y); o1[2] = f2h(c.z); o1[3] = f2h(c.w);
    o1[4] = f2h(d.x); o1[5] = f2h(d.y); o1[6] = f2h(d.z); o1[7] = f2h(d.w);
    *(us8*)(xb + cid * 16)     = o0;
    *(us8*)(xb + cid * 16 + 8) = o1;
    return;
  }
  const int bx = blockIdx.x % 96;     // n-tile
  const int by = blockIdx.x / 96;     // k-tile
  const int k0 = by * 64;
  const int n0 = bx * 128;
  const int w0 = n0 >> 3;       // first packed word column of tile
  const int g  = k0 >> 7;       // 64-k tile lies inside one group (GS=128)
  {
    // 64 rows x 16 words; thread = (row, 4-word chunk): one int4 load each
    int row = tid >> 2, qc = tid & 3;
    int4 v = *(const int4*)(qw + (size_t)(k0 + row) * NP + w0 + qc * 4);
    ldsQ[row * 16 + ((qc * 4 + 0) ^ (row & 15))] = v.x;
    ldsQ[row * 16 + ((qc * 4 + 1) ^ (row & 15))] = v.y;
    ldsQ[row * 16 + ((qc * 4 + 2) ^ (row & 15))] = v.z;
    ldsQ[row * 16 + ((qc * 4 + 3) ^ (row & 15))] = v.w;
  }
  if (tid < 16) ldsZ[tid] = qz[g * NP + w0 + tid];
  __syncthreads();
  const int nl  = tid >> 1;     // local n 0..127
  const int kh  = tid & 1;      // which 32-k half
  const int col = nl >> 3;
  const int j4  = (nl & 7) * 4;
  const int z   = (ldsZ[col] >> j4) & 0xF;
  const float s = sc[(size_t)g * N_DIM + n0 + nl];
  ushort_t* dst = wt + (size_t)(n0 + nl) * K_DIM + k0 + kh * 32;
#pragma unroll
  for (int c = 0; c < 4; ++c) {
    us8 o;
#pragma unroll
    for (int ii = 0; ii < 8; ++ii) {
      int row = kh * 32 + c * 8 + ii;
      int q = (ldsQ[row * 16 + (col ^ (row & 15))] >> j4) & 0xF;
      o[ii] = f2h((float)(q - z) * s);
    }
    *(us8*)(dst + c * 8) = o;
  }
}

// ---------------------------------------------------------------------------
// R5 GEMM: 256x256 tile, BK=64 (2 K-step units of 32), 512 threads = 8 waves
// (2m x 4n), wave tile 128x64 of mfma_f32_16x16x32_f16.
//
// R5 change vs R4 (443us, MfmaUtil 42%): R4's phase serialized the CU-level
// LDS drain (96 ds_read_b128 ~ 1152cy) against the MFMA cluster (~1242cy)
// because of the monolithic barrier+lgkmcnt(0) wall, and at 1 block/CU
// (128KiB LDS) no other block hides it. R5 = split-wait interleave:
//  - reads issued in consumption order (af0, bf0..3, af1..af7), order pinned
//    by sched_barrier(0) between reads,
//  - counted s_waitcnt lgkmcnt(7-i) before MFMA row i (covers exactly the
//    oldest 5+i reads) so rows 1..7 of MFMA hide the remaining drain,
//  - ONE barrier per phase (end only). Safety: end-of-phase vmcnt(8) leaves
//    units p+2,p+3 in flight and guarantees unit p+1 landed (RAW for next
//    phase's reads); reads of unit p are fully drained by this phase's last
//    lgkmcnt(0), before the end barrier, so stage(p+3) overwriting slot
//    (p-1)&3 next phase is WAR-safe.
//
// LDS ring: 4 units x 32KiB (unit = one 32-k step of A[256x32]+B[256x32]),
// unit u at slot u&3: A base = ((u>>1)&1)*32768 + (u&1)*8192, B = +16384.
// Per-row XOR bank swizzle on glds SOURCE + ds_read side (both-sides, R4,
// verified: bank conflicts = 0).

__device__ __forceinline__ void stage_unit(
    int u, const ushort_t* __restrict__ Ag, const ushort_t* __restrict__ Bg,
    int m0, int n0, int tid, ushort_t* lds) {
  const int t   = u >> 1;
  const int ks  = u & 1;
  const int b   = t & 1;
  const int kbu = t * 64 + ks * 32;            // k base of this unit
  const int r   = tid >> 1;                    // row 0..255 (2 threads/row)
  // dest is LINEAR (tid*16B); source k-half is inverse-swizzled so that the
  // data landing in slot (tid&1) is global half (tid&1)^((row>>2)&1).
  const int hp  = (tid & 1) ^ ((tid >> 3) & 1);
  const size_t ka = (size_t)kbu + hp * 8;
  ushort_t* dA = lds + b * 32768 + (2 * ks) * 4096 + tid * 8;
  ushort_t* dB = dA + 16384;
  const ushort_t* sA = Ag + (size_t)(m0 + r) * K_DIM + ka;
  const ushort_t* sB = Bg + (size_t)(n0 + r) * K_DIM + ka;
  GLDS16(sA,      dA);          // A slice 2ks
  GLDS16(sA + 16, dA + 4096);   // A slice 2ks+1
  GLDS16(sB,      dB);          // B slice 2ks
  GLDS16(sB + 16, dB + 4096);   // B slice 2ks+1
}

template <int N>
__device__ __forceinline__ void wait_lgkm() {
  if constexpr (N == 0)      asm volatile("s_waitcnt lgkmcnt(0)" ::: "memory");
  else if constexpr (N == 1) asm volatile("s_waitcnt lgkmcnt(1)" ::: "memory");
  else if constexpr (N == 2) asm volatile("s_waitcnt lgkmcnt(2)" ::: "memory");
  else if constexpr (N == 3) asm volatile("s_waitcnt lgkmcnt(3)" ::: "memory");
  else if constexpr (N == 4) asm volatile("s_waitcnt lgkmcnt(4)" ::: "memory");
  else if constexpr (N == 5) asm volatile("s_waitcnt lgkmcnt(5)" ::: "memory");
  else if constexpr (N == 6) asm volatile("s_waitcnt lgkmcnt(6)" ::: "memory");
  else if constexpr (N == 7) asm volatile("s_waitcnt lgkmcnt(7)" ::: "memory");
  __builtin_amdgcn_sched_barrier(0);   // rule 18: keep MFMAs below the wait
}

#define SB() __builtin_amdgcn_sched_barrier(0)

template <int VN, bool STG>
__device__ __forceinline__ void gemm_phase(
    int p, const ushort_t* __restrict__ Ag, const ushort_t* __restrict__ Bg,
    int m0, int n0, int tid, ushort_t* lds, f32x4 (&acc)[8][4]) {
  const int lane = tid & 63;
  const int wid  = tid >> 6;
  const int wm   = wid & 1;        // wave row (m) 0..1
  const int wn   = wid >> 1;       // wave col (n) 0..3
  const int ks   = p & 1;
  const int b    = (p >> 1) & 1;
  // A frag: row = lane&15, k = (lane>>4)*8 + j  (16x16x32 f16 layout).
  // chunk c = lane>>4 -> slice 2ks+(c>>1), k-half h=c&1, slot = h^((row>>2)&1).
  const int c  = lane >> 4;
  const int rl = lane & 15;
  const int sg = (c & 1) ^ ((rl >> 2) & 1);
  const ushort_t* base = lds + b * 32768 + (2 * ks + (c >> 1)) * 4096 + sg * 8;
  const ushort_t* pa = base + (wm * 128 + rl) * 16;
  const ushort_t* pb = base + 16384 + (wn * 64 + rl) * 16;
  half8 af[8], bf[4];
  // ---- issue reads in consumption order; SB pins issue order so counted
  //      lgkm waits map to the right registers.
  af[0] = *(const half8*)(pa);
  bf[0] = *(const half8*)(pb);
  bf[1] = *(const half8*)(pb + 256);
  bf[2] = *(const half8*)(pb + 512);
  bf[3] = *(const half8*)(pb + 768);
  SB();
  af[1] = *(const half8*)(pa + 256);  SB();
  af[2] = *(const half8*)(pa + 512);  SB();
  af[3] = *(const half8*)(pa + 768);  SB();
  af[4] = *(const half8*)(pa + 1024); SB();
  af[5] = *(const half8*)(pa + 1280); SB();
  af[6] = *(const half8*)(pa + 1536); SB();
  af[7] = *(const half8*)(pa + 1792); SB();
  if constexpr (STG) stage_unit(p + 3, Ag, Bg, m0, n0, tid, lds);
  __builtin_amdgcn_s_setprio(1);
#define MFMA_ROW(i, W)                                                       \
  wait_lgkm<W>();                                                            \
  acc[i][0] = __builtin_amdgcn_mfma_f32_16x16x32_f16(af[i], bf[0], acc[i][0], 0, 0, 0); \
  acc[i][1] = __builtin_amdgcn_mfma_f32_16x16x32_f16(af[i], bf[1], acc[i][1], 0, 0, 0); \
  acc[i][2] = __builtin_amdgcn_mfma_f32_16x16x32_f16(af[i], bf[2], acc[i][2], 0, 0, 0); \
  acc[i][3] = __builtin_amdgcn_mfma_f32_16x16x32_f16(af[i], bf[3], acc[i][3], 0, 0, 0)
  MFMA_ROW(0, 7);
  MFMA_ROW(1, 6);
  MFMA_ROW(2, 5);
  MFMA_ROW(3, 4);
  MFMA_ROW(4, 3);
  MFMA_ROW(5, 2);
  MFMA_ROW(6, 1);
  MFMA_ROW(7, 0);
#undef MFMA_ROW
  __builtin_amdgcn_s_setprio(0);
  if constexpr (VN == 8)      asm volatile("s_waitcnt vmcnt(8)" ::: "memory");
  else if constexpr (VN == 4) asm volatile("s_waitcnt vmcnt(4)" ::: "memory");
  else if constexpr (VN == 0) asm volatile("s_waitcnt vmcnt(0)" ::: "memory");
  if constexpr (VN >= 0) {
    __builtin_amdgcn_s_barrier();
    asm volatile("" ::: "memory");     // fence: next phase's ds_reads stay below
  }
}

__global__ __launch_bounds__(512, 2) void gemm256_kernel(
    const ushort_t* __restrict__ Xb, const ushort_t* __restrict__ Wt,
    const float* __restrict__ bias, float* __restrict__ out) {
  __shared__ __align__(16) ushort_t lds[65536];   // 128 KiB, ring of 4 units
  const int tid = threadIdx.x;
  const int m0  = blockIdx.x * 256;   // m fastest: B panel shared by x-row
  const int n0  = blockIdx.y * 256;
  f32x4 acc[8][4] = {};

  // prologue: units 0,1,2 in flight; vmcnt(8) -> unit 0 landed
  stage_unit(0, Xb, Wt, m0, n0, tid, lds);
  stage_unit(1, Xb, Wt, m0, n0, tid, lds);
  stage_unit(2, Xb, Wt, m0, n0, tid, lds);
  asm volatile("s_waitcnt vmcnt(8)" ::: "memory");
  __builtin_amdgcn_s_barrier();
  asm volatile("" ::: "memory");

  // 128 phases = 64 K-tiles x 2 K-steps. Unroll 4 folds buf/ks indices.
#pragma unroll 4
  for (int p = 0; p < 125; ++p)
    gemm_phase<8, true>(p, Xb, Wt, m0, n0, tid, lds, acc);
  gemm_phase<4,  false>(125, Xb, Wt, m0, n0, tid, lds, acc);
  gemm_phase<0,  false>(126, Xb, Wt, m0, n0, tid, lds, acc);
  gemm_phase<-1, false>(127, Xb, Wt, m0, n0, tid, lds, acc);

  // epilogue: 16x16 C/D layout col=lane&15, row=(lane>>4)*4+reg [m89].
  const int lane = tid & 63;
  const int wm   = (tid >> 6) & 1;
  const int wn   = tid >> 7;
#pragma unroll
  for (int jj = 0; jj < 4; ++jj) {
    int n = n0 + wn * 64 + jj * 16 + (lane & 15);
    float bv = bias[n];
#pragma unroll
    for (int i = 0; i < 8; ++i) {
      int mb = (int)(m0 + wm * 128 + i * 16 + ((lane >> 4) << 2));
#pragma unroll
      for (int r = 0; r < 4; ++r)
        __builtin_nontemporal_store(acc[i][jj][r] + bv,
                                    out + (size_t)(mb + r) * N_DIM + n);
    }
  }
}

// ---------------------------------------------------------------------------
// Fallback GEMM (R3): 128x128x64 block tile, 32x32x16 MFMA — used only when
// the workspace is too small for the materialized-Wt/Xb fast path.
template <int APRE, int BPRE>
__global__ __launch_bounds__(256) void gemm_kernel(
    const ushort_t* __restrict__ Xb, const float* __restrict__ Xf,
    const ushort_t* __restrict__ Wt,
    const int* __restrict__ qw, const int* __restrict__ qz,
    const float* __restrict__ sc,
    const float* __restrict__ bias, float* __restrict__ out) {
  __shared__ __align__(16) ushort_t lsA[128 * 64];
  __shared__ __align__(16) ushort_t lsB[128 * 64];
  const int tid  = threadIdx.x;
  const int lane = tid & 63;
  const int wid  = tid >> 6;
  const int wm   = wid & 1;
  const int wn   = wid >> 1;
  const int m0   = blockIdx.x * 128;
  const int n0   = blockIdx.y * 128;

  f32x16 acc[2][2] = {};

  for (int kt = 0; kt < K_DIM / 64; ++kt) {
    const int kb = kt * 64;
    if constexpr (APRE) {
#pragma unroll
      for (int i = 0; i < 4; ++i) {
        int cid = i * 256 + tid;
        int r = cid >> 3, scol = cid & 7;
        int c = scol ^ (r & 7);
        GLDS16(Xb + (size_t)(m0 + r) * K_DIM + kb + c * 8, lsA + cid * 8);
      }
    } else {
#pragma unroll
      for (int i = 0; i < 4; ++i) {
        int cid = i * 256 + tid;
        int r = cid >> 3, scol = cid & 7;
        int c = scol ^ (r & 7);
        const float* src = Xf + (size_t)(m0 + r) * K_DIM + kb + c * 8;
        float4 a = *(const float4*)src;
        float4 b = *(const float4*)(src + 4);
        us8 o;
        o[0] = f2h(a.x); o[1] = f2h(a.y); o[2] = f2h(a.z); o[3] = f2h(a.w);
        o[4] = f2h(b.x); o[5] = f2h(b.y); o[6] = f2h(b.z); o[7] = f2h(b.w);
        *(us8*)(lsA + cid * 8) = o;
      }
    }
    if constexpr (BPRE) {
#pragma unroll
      for (int i = 0; i < 4; ++i) {
        int cid = i * 256 + tid;
        int r = cid >> 3, scol = cid & 7;
        int c = scol ^ (r & 7);
        GLDS16(Wt + (size_t)(n0 + r) * K_DIM + kb + c * 8, lsB + cid * 8);
      }
    } else {
#pragma unroll
      for (int i = 0; i < 4; ++i) {
        int wi = i * 256 + tid;
        int kl = wi >> 4, cw = wi & 15;
        int k = kb + kl;
        int g = k >> 7;
        int qword = qw[(size_t)k * NP + (n0 >> 3) + cw];
        int zword = qz[g * NP + (n0 >> 3) + cw];
        float4 s0 = *(const float4*)(sc + (size_t)g * N_DIM + n0 + cw * 8);
        float4 s1 = *(const float4*)(sc + (size_t)g * N_DIM + n0 + cw * 8 + 4);
        float sv[8] = {s0.x, s0.y, s0.z, s0.w, s1.x, s1.y, s1.z, s1.w};
#pragma unroll
        for (int j = 0; j < 8; ++j) {
          int nl = cw * 8 + j;
          int q = (qword >> (4 * j)) & 0xF;
          int z = (zword >> (4 * j)) & 0xF;
          lsB[nl * 64 + (((kl >> 3) ^ (nl & 7)) << 3) + (kl & 7)] =
              f2h((float)(q - z) * sv[j]);
        }
      }
    }
    __syncthreads();
#pragma unroll
    for (int ks = 0; ks < 4; ++ks) {
      half8 af[2], bfr[2];
      const int h = lane >> 5;
      const int c = ks * 2 + h;
#pragma unroll
      for (int i = 0; i < 2; ++i) {
        int row = wm * 64 + i * 32 + (lane & 31);
        af[i] = *(const half8*)(lsA + (row * 8 + (c ^ (row & 7))) * 8);
      }
#pragma unroll
      for (int jj = 0; jj < 2; ++jj) {
        int row = wn * 64 + jj * 32 + (lane & 31);
        bfr[jj] = *(const half8*)(lsB + (row * 8 + (c ^ (row & 7))) * 8);
      }
#pragma unroll
      for (int i = 0; i < 2; ++i)
#pragma unroll
        for (int jj = 0; jj < 2; ++jj)
          acc[i][jj] = __builtin_amdgcn_mfma_f32_32x32x16_f16(
              af[i], bfr[jj], acc[i][jj], 0, 0, 0);
    }
    __syncthreads();
  }

#pragma unroll
  for (int jj = 0; jj < 2; ++jj) {
    int n = n0 + wn * 64 + jj * 32 + (lane & 31);
    float bv = bias[n];
#pragma unroll
    for (int i = 0; i < 2; ++i) {
      int mbase = m0 + wm * 64 + i * 32 + ((lane >> 5) << 2);
#pragma unroll
      for (int reg = 0; reg < 16; ++reg) {
        int m = mbase + (reg & 3) + ((reg >> 2) << 3);
        __builtin_nontemporal_store(acc[i][jj][reg] + bv,
                                    out + (size_t)m * N_DIM + n);
      }
    }
  }
}

// ---------------------------------------------------------------------------
extern "C" void kernel_launch(void* const* d_in, const int* in_sizes, int n_in,
                              void* d_out, int out_size, void* d_ws, size_t ws_size,
                              hipStream_t stream) {
  const float* x    = (const float*)d_in[0];
  const int*   qw   = (const int*)d_in[1];
  const int*   qz   = (const int*)d_in[2];
  const float* sc   = (const float*)d_in[3];
  const float* bias = (const float*)d_in[4];
  float*       out  = (float*)d_out;
  // d_in[5] = groupsize (=128, hardcoded)

  const size_t WT_BYTES = (size_t)N_DIM * K_DIM * 2;  // 96 MiB
  const size_t XB_BYTES = (size_t)M_DIM * K_DIM * 2;  // 32 MiB
  ushort_t* Wt = (ushort_t*)d_ws;
  ushort_t* Xb = (ushort_t*)((char*)d_ws + WT_BYTES);
  const bool hasWt = ws_size >= WT_BYTES;
  const bool hasXb = ws_size >= WT_BYTES + XB_BYTES;

  if (hasXb) {
    prep_kernel<<<DQ_BLOCKS + CVT_BLOCKS, 256, 0, stream>>>(qw, qz, sc, Wt, x, Xb);
    dim3 grid256(M_DIM / 256, N_DIM / 256);  // (16, 48): m fastest
    gemm256_kernel<<<grid256, 512, 0, stream>>>(Xb, Wt, bias, out);
  } else if (hasWt) {
    dim3 grid(M_DIM / 128, N_DIM / 128);
    prep_kernel<<<DQ_BLOCKS, 256, 0, stream>>>(qw, qz, sc, Wt, x, nullptr);
    gemm_kernel<0, 1><<<grid, 256, 0, stream>>>(nullptr, x, Wt, qw, qz, sc, bias, out);
  } else {
    dim3 grid(M_DIM / 128, N_DIM / 128);
    gemm_kernel<0, 0><<<grid, 256, 0, stream>>>(nullptr, x, nullptr, qw, qz, sc, bias, out);
  }
}